// Round 4
// baseline (350.521 us; speedup 1.0000x reference)
//
#include <hip/hip_runtime.h>

#define HW 4096
#define NC 256
#define NB 8
#define GN_EPS 1e-5f

typedef short bf16x8 __attribute__((ext_vector_type(8)));
typedef float f32x4 __attribute__((ext_vector_type(4)));

#define MFMA16 __builtin_amdgcn_mfma_f32_16x16x32_bf16

// swizzle used only by qkv/outproj staging tiles (unchanged from r3)
#define SWZ(row) ((((row) & 7) ^ (((row) >> 3) & 7)) << 4)

// q-scale folds 1/sqrt(256) AND log2(e) so softmax runs in base-2.
#define QSCALE 0.09016844f

__device__ __forceinline__ unsigned short f2bf(float f) {
  unsigned int u = __float_as_uint(f);
  u = (u + 0x7FFFu + ((u >> 16) & 1u)) >> 16;
  return (unsigned short)u;
}
__device__ __forceinline__ float bf2f(unsigned short h) {
  return __uint_as_float(((unsigned int)h) << 16);
}

__device__ __forceinline__ void gload16(const void* g, void* l) {
  __builtin_amdgcn_global_load_lds(
      (const __attribute__((address_space(1))) void*)g,
      (__attribute__((address_space(3))) void*)l, 16, 0, 0);
}

// ---------------------------------------------------------------- kernel 1
__global__ void gn_stats_kernel(const float* __restrict__ x,
                                const float* __restrict__ gnw,
                                const float* __restrict__ gnb,
                                float* __restrict__ s_arr,
                                float* __restrict__ t_arr) {
  int bg = blockIdx.x;
  int b = bg >> 5, g = bg & 31;
  const float4* base = (const float4*)(x + ((size_t)b * NC + g * 8) * HW);
  int tid = threadIdx.x;
  float s = 0.f, ss = 0.f;
  for (int it = 0; it < 32; ++it) {
    float4 v = base[tid + it * 256];
    s += v.x + v.y + v.z + v.w;
    ss += v.x * v.x + v.y * v.y + v.z * v.z + v.w * v.w;
  }
  for (int off = 32; off; off >>= 1) {
    s += __shfl_down(s, off);
    ss += __shfl_down(ss, off);
  }
  __shared__ float red[8];
  __shared__ float bc[2];
  int wave = tid >> 6, lane = tid & 63;
  if (lane == 0) { red[wave] = s; red[4 + wave] = ss; }
  __syncthreads();
  if (tid == 0) {
    float S = red[0] + red[1] + red[2] + red[3];
    float SS = red[4] + red[5] + red[6] + red[7];
    float mean = S * (1.f / 32768.f);
    float var = SS * (1.f / 32768.f) - mean * mean;
    bc[0] = mean;
    bc[1] = rsqrtf(var + GN_EPS);
  }
  __syncthreads();
  if (tid < 8) {
    int c = g * 8 + tid;
    float sv = bc[1] * gnw[c];
    s_arr[b * NC + c] = sv;
    t_arr[b * NC + c] = gnb[c] - bc[0] * sv;
  }
}

// ---------------------------------------------------------------- kernel 2
// QKV GEMM. q -> qb[p][c] (scaled), k -> CHUNKED kc_[b][ch=c/8][p][e=c&7],
// v -> vb[p][c] (plain; transposed to chunks by kernel 3).
__global__ __launch_bounds__(256) void qkv_gemm_kernel(
    const float* __restrict__ x, const float* __restrict__ s_arr,
    const float* __restrict__ t_arr, const float* __restrict__ w,
    const float* __restrict__ bias, unsigned short* __restrict__ qb,
    unsigned short* __restrict__ kc_, unsigned short* __restrict__ vb) {
  int b = blockIdx.z;
  int p0 = blockIdx.x * 64;
  int o0 = blockIdx.y * 128;
  int tid = threadIdx.x;
  int wave = tid >> 6, lane = tid & 63;
  int l15 = lane & 15, q4 = lane >> 4;
  int wm = wave >> 1, wn = wave & 1;
  __shared__ unsigned short a_lds[64 * 64];
  __shared__ unsigned short b_lds[128 * 64];
  char* aB = (char*)a_lds;
  char* bB = (char*)b_lds;
  f32x4 acc[2][4];
  for (int i = 0; i < 2; ++i)
    for (int j = 0; j < 4; ++j) acc[i][j] = (f32x4){0.f, 0.f, 0.f, 0.f};

  for (int kc0 = 0; kc0 < 256; kc0 += 64) {
    __syncthreads();
    for (int it = 0; it < 4; ++it) {
      int idx = tid + it * 256;
      int c = idx >> 4, p4 = idx & 15;
      float4 xv = *(const float4*)(x + ((size_t)b * NC + kc0 + c) * HW + p0 + p4 * 4);
      float sc = s_arr[b * NC + kc0 + c];
      float tc = t_arr[b * NC + kc0 + c];
      float vals[4] = {xv.x, xv.y, xv.z, xv.w};
      for (int i = 0; i < 4; ++i) {
        int p = p4 * 4 + i;
        *(unsigned short*)(aB + ((p * 128 + c * 2) ^ SWZ(p))) =
            f2bf(vals[i] * sc + tc);
      }
    }
    for (int it = 0; it < 8; ++it) {
      int idx = tid + it * 256;
      int o = idx >> 4, c4 = idx & 15;
      float4 wv = *(const float4*)(w + (size_t)(o0 + o) * NC + kc0 + c4 * 4);
      ushort4 hv = make_ushort4(f2bf(wv.x), f2bf(wv.y), f2bf(wv.z), f2bf(wv.w));
      *(ushort4*)(bB + ((o * 128 + c4 * 8) ^ SWZ(o))) = hv;
    }
    __syncthreads();
    for (int kk = 0; kk < 2; ++kk) {
      bf16x8 af[2], bfv[4];
      for (int pb = 0; pb < 2; ++pb) {
        int row = wm * 32 + pb * 16 + l15;
        af[pb] = *(const bf16x8*)(aB + ((row * 128 + kk * 64 + q4 * 16) ^ SWZ(row)));
      }
      for (int ob = 0; ob < 4; ++ob) {
        int row = wn * 64 + ob * 16 + l15;
        bfv[ob] = *(const bf16x8*)(bB + ((row * 128 + kk * 64 + q4 * 16) ^ SWZ(row)));
      }
      for (int pb = 0; pb < 2; ++pb)
        for (int ob = 0; ob < 4; ++ob)
          acc[pb][ob] = MFMA16(af[pb], bfv[ob], acc[pb][ob], 0, 0, 0);
    }
  }
  for (int pb = 0; pb < 2; ++pb) {
    for (int ob = 0; ob < 4; ++ob) {
      int og = o0 + wn * 64 + ob * 16 + l15;
      int tsel = og >> 8, oc = og & 255;
      float bi = bias[og];
      for (int r = 0; r < 4; ++r) {
        int p = p0 + wm * 32 + pb * 16 + q4 * 4 + r;
        float val = acc[pb][ob][r] + bi;
        if (tsel == 0) {
          qb[((size_t)b * HW + p) * NC + oc] = f2bf(val * QSCALE);
        } else if (tsel == 1) {
          kc_[((size_t)(b * 32 + (oc >> 3)) * HW + p) * 8 + (oc & 7)] = f2bf(val);
        } else {
          vb[((size_t)b * HW + p) * NC + oc] = f2bf(val);
        }
      }
    }
  }
}

// ---------------------------------------------------------------- kernel 3
// vb[p][c] -> vc[b][jcg=p/8][c][e=p&7]  (chunked, flash-staging-ready)
__global__ void transpose_v_kernel(const unsigned short* __restrict__ vb,
                                   unsigned short* __restrict__ vc) {
  int b = blockIdx.z;
  int p0 = blockIdx.x * 64, c0 = blockIdx.y * 64;
  int tid = threadIdx.x;
  __shared__ unsigned short tl[64 * 64];  // [c][p] swizzled
  char* tB = (char*)tl;
  for (int rep = 0; rep < 2; ++rep) {
    int p = (tid >> 3) + rep * 32;
    int c8 = (tid & 7) * 8;
    uint4 raw = *(const uint4*)(vb + ((size_t)b * HW + p0 + p) * NC + c0 + c8);
    unsigned int rr[4] = {raw.x, raw.y, raw.z, raw.w};
    for (int i = 0; i < 4; ++i) {
      int c_a = c8 + i * 2, c_b = c8 + i * 2 + 1;
      *(unsigned short*)(tB + ((c_a * 128 + p * 2) ^ SWZ(c_a))) =
          (unsigned short)(rr[i] & 0xffffu);
      *(unsigned short*)(tB + ((c_b * 128 + p * 2) ^ SWZ(c_b))) =
          (unsigned short)(rr[i] >> 16);
    }
  }
  __syncthreads();
  for (int rep = 0; rep < 2; ++rep) {
    int c = (tid >> 3) + rep * 32;
    int jc8 = tid & 7;
    bf16x8 val = *(const bf16x8*)(tB + ((c * 128 + jc8 * 16) ^ SWZ(c)));
    *(bf16x8*)(vc + (((size_t)b * 512 + (p0 >> 3) + jc8) * 256 + c0 + c) * 8) = val;
  }
}

// ---------------------------------------------------------------- kernel 4
// Flash attention v4: 8 waves x 32 q-rows = 256 rows/block; j split in 2
// halves (2048 each, 32 tiles of 64) -> 256 blocks. Chunked conflict-free
// LDS layouts, frag addresses = 1 base VGPR + immediates. K dbuf (2x32KB),
// V single-buffered (32KB), per-wave P (4KB). Writes normalized partial O
// (bf16) + L = m + log2(l) per row; merged in outproj.
__global__ __launch_bounds__(512, 2) void flash_attn_kernel(
    const unsigned short* __restrict__ qb, const unsigned short* __restrict__ kc_,
    const unsigned short* __restrict__ vc, unsigned short* __restrict__ Oh0,
    unsigned short* __restrict__ Oh1, float* __restrict__ Lb) {
  int b = blockIdx.x & 7;
  int rest = blockIdx.x >> 3;
  int half = rest & 1;
  int qt = rest >> 1;  // 0..15
  int tid = threadIdx.x;
  int wave = tid >> 6, lane = tid & 63;
  int l15 = lane & 15, q4 = lane >> 4;

  __shared__ unsigned short k_lds[2][32 * 64 * 8];  // [buf][ch][j][e]
  __shared__ unsigned short v_lds[8 * 256 * 8];     // [jc][c][e]
  __shared__ unsigned short p_lds[8][8 * 32 * 8];   // per-wave [jc][q][e]

  const char* kcb = (const char*)(kc_ + (size_t)b * 32 * HW * 8);
  const char* vcb = (const char*)(vc + (size_t)b * 512 * NC * 8);

  int lane16 = lane * 16;
  char* pB = (char*)p_lds[wave];

  // frag per-lane bases (all reads conflict-free contiguous)
  int kbo = q4 * 1024 + l15 * 16;
  int vbo = q4 * 4096 + l15 * 16;
  int prd = q4 * 512 + ((l15 * 16) ^ ((l15 >> 3) << 5));
  int pwr = (l15 >> 3) * 512 + (l15 & 7) * 2 + q4 * 64;
  int rxor = (q4 >> 1) << 1;

  bf16x8 qf[2][8];
#pragma unroll
  for (int rf = 0; rf < 2; ++rf) {
    const unsigned short* qrow =
        qb + ((size_t)b * HW + qt * 256 + wave * 32 + rf * 16 + l15) * NC;
#pragma unroll
    for (int kc = 0; kc < 8; ++kc)
      qf[rf][kc] = *(const bf16x8*)(qrow + kc * 32 + q4 * 8);
  }

  f32x4 acc[2][16];
#pragma unroll
  for (int rf = 0; rf < 2; ++rf)
#pragma unroll
    for (int nb = 0; nb < 16; ++nb) acc[rf][nb] = (f32x4){0.f, 0.f, 0.f, 0.f};
  float m_r[2][4], l_r[2][4];
#pragma unroll
  for (int rf = 0; rf < 2; ++rf)
#pragma unroll
    for (int r = 0; r < 4; ++r) { m_r[rf][r] = -1e30f; l_r[rf][r] = 0.f; }

  int j0b = half * 2048;

  {  // prologue: stage K tile 0 (chunks wave*4 .. +3)
    int ch = wave * 4;
#pragma unroll
    for (int i = 0; i < 4; ++i)
      gload16(kcb + (size_t)(ch + i) * 65536 + j0b * 16 + lane16,
              (char*)k_lds[0] + (ch + i) * 1024);
  }
  __syncthreads();

  for (int t = 0; t < 32; ++t) {
    int cur = t & 1;
    int j0 = j0b + t * 64;
    {  // stage V(t) (single buffer; prev PV done at loop-end barrier)
      int id0 = wave * 4;
#pragma unroll
      for (int i = 0; i < 4; ++i) {
        int id = id0 + i, jc = id >> 2, cs = id & 3;
        gload16(vcb + (size_t)(j0 >> 3) * 4096 + jc * 4096 + cs * 1024 + lane16,
                (char*)v_lds + jc * 4096 + cs * 1024);
      }
    }
    if (t < 31) {  // stage K(t+1) into other buffer
      int ch = wave * 4;
#pragma unroll
      for (int i = 0; i < 4; ++i)
        gload16(kcb + (size_t)(ch + i) * 65536 + (j0 + 64) * 16 + lane16,
                (char*)k_lds[cur ^ 1] + (ch + i) * 1024);
    }
    const char* kB = (const char*)k_lds[cur];

    // S = Q K^T for both 16-row blocks; each K-frag feeds 2 MFMAs
    f32x4 sv[2][4];
    __builtin_amdgcn_s_setprio(1);
#pragma unroll
    for (int jb = 0; jb < 4; ++jb) {
      f32x4 a0 = (f32x4){0.f, 0.f, 0.f, 0.f};
      f32x4 a1 = (f32x4){0.f, 0.f, 0.f, 0.f};
#pragma unroll
      for (int kc = 0; kc < 8; ++kc) {
        bf16x8 kf = *(const bf16x8*)(kB + kbo + kc * 4096 + jb * 256);
        a0 = MFMA16(qf[0][kc], kf, a0, 0, 0, 0);
        a1 = MFMA16(qf[1][kc], kf, a1, 0, 0, 0);
      }
      sv[0][jb] = a0;
      sv[1][jb] = a1;
    }
    __builtin_amdgcn_s_setprio(0);

#pragma unroll
    for (int rf = 0; rf < 2; ++rf) {
      float pmax[4];
#pragma unroll
      for (int r = 0; r < 4; ++r) {
        float mx = fmaxf(fmaxf(sv[rf][0][r], sv[rf][1][r]),
                         fmaxf(sv[rf][2][r], sv[rf][3][r]));
        mx = fmaxf(mx, __shfl_xor(mx, 1));
        mx = fmaxf(mx, __shfl_xor(mx, 2));
        mx = fmaxf(mx, __shfl_xor(mx, 4));
        mx = fmaxf(mx, __shfl_xor(mx, 8));
        pmax[r] = mx;
      }
      float worst = fmaxf(fmaxf(pmax[0] - m_r[rf][0], pmax[1] - m_r[rf][1]),
                          fmaxf(pmax[2] - m_r[rf][2], pmax[3] - m_r[rf][3]));
      if (!__all(worst <= 12.0f)) {
        float sf[4];
#pragma unroll
        for (int r = 0; r < 4; ++r) {
          float mn = fmaxf(m_r[rf][r], pmax[r]);
          sf[r] = exp2f(m_r[rf][r] - mn);
          m_r[rf][r] = mn;
          l_r[rf][r] *= sf[r];
        }
#pragma unroll
        for (int nb = 0; nb < 16; ++nb) {
          f32x4 tv = acc[rf][nb];
          tv[0] *= sf[0]; tv[1] *= sf[1]; tv[2] *= sf[2]; tv[3] *= sf[3];
          acc[rf][nb] = tv;
        }
      }
#pragma unroll
      for (int r = 0; r < 4; ++r) {
        float rs = 0.f;
#pragma unroll
        for (int jb = 0; jb < 4; ++jb) {
          float p = exp2f(sv[rf][jb][r] - m_r[rf][r]);
          sv[rf][jb][r] = p;
          rs += p;
        }
        rs += __shfl_xor(rs, 1);
        rs += __shfl_xor(rs, 2);
        rs += __shfl_xor(rs, 4);
        rs += __shfl_xor(rs, 8);
        l_r[rf][r] += rs;
      }
      // P-write (conflict-spread via row-slot xor)
#pragma unroll
      for (int jb = 0; jb < 4; ++jb)
#pragma unroll
        for (int r = 0; r < 4; ++r)
          *(unsigned short*)(pB + pwr + jb * 1024 + rf * 256 +
                             ((r ^ rxor) * 16)) = f2bf(sv[rf][jb][r]);
    }

    bf16x8 pa[2][2];
#pragma unroll
    for (int rf = 0; rf < 2; ++rf)
#pragma unroll
      for (int kj = 0; kj < 2; ++kj)
        pa[rf][kj] = *(const bf16x8*)(pB + prd + kj * 2048 + rf * 256);

    __syncthreads();  // V(t) + K(t+1) landed (vmcnt drain)

    __builtin_amdgcn_s_setprio(1);
#pragma unroll
    for (int nb = 0; nb < 16; ++nb) {
#pragma unroll
      for (int kj = 0; kj < 2; ++kj) {
        bf16x8 vf = *(const bf16x8*)((const char*)v_lds + vbo + kj * 16384 + nb * 256);
        acc[0][nb] = MFMA16(pa[0][kj], vf, acc[0][nb], 0, 0, 0);
        acc[1][nb] = MFMA16(pa[1][kj], vf, acc[1][nb], 0, 0, 0);
      }
    }
    __builtin_amdgcn_s_setprio(0);
    __syncthreads();  // PV done -> v_lds free for t+1
  }

  unsigned short* Ohp = half ? Oh1 : Oh0;
  float* Lp = Lb + (size_t)half * NB * HW;
#pragma unroll
  for (int rf = 0; rf < 2; ++rf) {
    float inv[4];
#pragma unroll
    for (int r = 0; r < 4; ++r) inv[r] = 1.f / l_r[rf][r];
#pragma unroll
    for (int nb = 0; nb < 16; ++nb)
#pragma unroll
      for (int r = 0; r < 4; ++r) {
        int q = qt * 256 + wave * 32 + rf * 16 + q4 * 4 + r;
        Ohp[((size_t)b * HW + q) * NC + nb * 16 + l15] =
            f2bf(acc[rf][nb][r] * inv[r]);
      }
    if (l15 == 0) {
#pragma unroll
      for (int r = 0; r < 4; ++r) {
        int q = qt * 256 + wave * 32 + rf * 16 + q4 * 4 + r;
        Lp[(size_t)b * HW + q] = m_r[rf][r] + log2f(l_r[rf][r]);
      }
    }
  }
}

// ---------------------------------------------------------------- kernel 5
// out = out_w @ merged_att^T + out_b + x; partial-O merge fused into staging.
__global__ __launch_bounds__(256) void outproj_kernel(
    const float* __restrict__ ow, const float* __restrict__ obias,
    const unsigned short* __restrict__ Oh0, const unsigned short* __restrict__ Oh1,
    const float* __restrict__ Lb, const float* __restrict__ x,
    float* __restrict__ out) {
  int b = blockIdx.y;
  int p0 = blockIdx.x * 64;
  int tid = threadIdx.x;
  int wave = tid >> 6, lane = tid & 63;
  int l15 = lane & 15, q4 = lane >> 4;
  __shared__ unsigned short aw_lds[256 * 64];
  __shared__ unsigned short bt_lds[64 * 64];
  char* aB = (char*)aw_lds;
  char* bB = (char*)bt_lds;
  f32x4 acc[4][4];
  for (int i = 0; i < 4; ++i)
    for (int j = 0; j < 4; ++j) acc[i][j] = (f32x4){0.f, 0.f, 0.f, 0.f};

  for (int kc0 = 0; kc0 < 256; kc0 += 64) {
    __syncthreads();
    for (int it = 0; it < 16; ++it) {
      int idx = tid + it * 256;
      int o = idx >> 4, c4 = idx & 15;
      float4 wv = *(const float4*)(ow + (size_t)o * NC + kc0 + c4 * 4);
      ushort4 hv = make_ushort4(f2bf(wv.x), f2bf(wv.y), f2bf(wv.z), f2bf(wv.w));
      *(ushort4*)(aB + ((o * 128 + c4 * 8) ^ SWZ(o))) = hv;
    }
    for (int it = 0; it < 2; ++it) {
      int idx = tid + it * 256;
      int p = idx >> 3, c8i = idx & 7;
      int row = p0 + p;
      float L1 = Lb[(size_t)b * HW + row];
      float L2 = Lb[(size_t)(NB + b) * HW + row];
      float w1 = 1.f / (1.f + exp2f(L2 - L1));
      float w2 = 1.f - w1;
      const unsigned short* o1p = Oh0 + ((size_t)b * HW + row) * NC + kc0 + c8i * 8;
      const unsigned short* o2p = Oh1 + ((size_t)b * HW + row) * NC + kc0 + c8i * 8;
      uint4 ra = *(const uint4*)o1p;
      uint4 rb = *(const uint4*)o2p;
      unsigned int aw[4] = {ra.x, ra.y, ra.z, ra.w};
      unsigned int bw[4] = {rb.x, rb.y, rb.z, rb.w};
      unsigned int outw[4];
      for (int i = 0; i < 4; ++i) {
        float lo = w1 * bf2f((unsigned short)(aw[i] & 0xffffu)) +
                   w2 * bf2f((unsigned short)(bw[i] & 0xffffu));
        float hi = w1 * bf2f((unsigned short)(aw[i] >> 16)) +
                   w2 * bf2f((unsigned short)(bw[i] >> 16));
        outw[i] = (unsigned int)f2bf(lo) | ((unsigned int)f2bf(hi) << 16);
      }
      *(uint4*)(bB + ((p * 128 + c8i * 16) ^ SWZ(p))) =
          make_uint4(outw[0], outw[1], outw[2], outw[3]);
    }
    __syncthreads();
    for (int kk = 0; kk < 2; ++kk) {
      bf16x8 af[4], bfv[4];
      for (int obk = 0; obk < 4; ++obk) {
        int row = wave * 64 + obk * 16 + l15;
        af[obk] = *(const bf16x8*)(aB + ((row * 128 + kk * 64 + q4 * 16) ^ SWZ(row)));
      }
      for (int pb = 0; pb < 4; ++pb) {
        int row = pb * 16 + l15;
        bfv[pb] = *(const bf16x8*)(bB + ((row * 128 + kk * 64 + q4 * 16) ^ SWZ(row)));
      }
      for (int obk = 0; obk < 4; ++obk)
        for (int pb = 0; pb < 4; ++pb)
          acc[obk][pb] = MFMA16(af[obk], bfv[pb], acc[obk][pb], 0, 0, 0);
    }
  }
  for (int obk = 0; obk < 4; ++obk)
    for (int pb = 0; pb < 4; ++pb)
      for (int r = 0; r < 4; ++r) {
        int o = wave * 64 + obk * 16 + q4 * 4 + r;
        int p = p0 + pb * 16 + l15;
        size_t gi = ((size_t)b * NC + o) * HW + p;
        out[gi] = acc[obk][pb][r] + obias[o] + x[gi];
      }
}

// ---------------------------------------------------------------- launch
extern "C" void kernel_launch(void* const* d_in, const int* in_sizes, int n_in,
                              void* d_out, int out_size, void* d_ws, size_t ws_size,
                              hipStream_t stream) {
  (void)in_sizes; (void)n_in; (void)out_size; (void)ws_size;
  const float* x = (const float*)d_in[0];
  const float* gnw = (const float*)d_in[1];
  const float* gnb = (const float*)d_in[2];
  const float* qkvw = (const float*)d_in[3];
  const float* qkvb = (const float*)d_in[4];
  const float* ow = (const float*)d_in[5];
  const float* obias = (const float*)d_in[6];
  float* out = (float*)d_out;

  char* ws = (char*)d_ws;
  float* s_arr = (float*)ws;
  float* t_arr = s_arr + NB * NC;
  size_t tsz = (size_t)NB * HW * NC;  // 8M ushort = 16MB
  unsigned short* qb = (unsigned short*)(ws + 16384);
  unsigned short* kc_ = qb + tsz;
  unsigned short* vb = kc_ + tsz;      // plain V; reused as Oh0 after transpose
  unsigned short* vc = vb + tsz;
  unsigned short* Oh1 = vc + tsz;
  float* Lb = (float*)(Oh1 + tsz);     // 2*NB*HW f32 = 256KB
  unsigned short* Oh0 = vb;            // reuse

  hipLaunchKernelGGL(gn_stats_kernel, dim3(NB * 32), dim3(256), 0, stream,
                     x, gnw, gnb, s_arr, t_arr);
  hipLaunchKernelGGL(qkv_gemm_kernel, dim3(64, 6, NB), dim3(256), 0, stream,
                     x, s_arr, t_arr, qkvw, qkvb, qb, kc_, vb);
  hipLaunchKernelGGL(transpose_v_kernel, dim3(64, 4, NB), dim3(256), 0, stream,
                     vb, vc);
  hipLaunchKernelGGL(flash_attn_kernel, dim3(256), dim3(512), 0, stream,
                     qb, kc_, vc, Oh0, Oh1, Lb);
  hipLaunchKernelGGL(outproj_kernel, dim3(64, NB), dim3(256), 0, stream,
                     ow, obias, Oh0, Oh1, Lb, x, out);
}

// Round 5
// 265.328 us; speedup vs baseline: 1.3211x; 1.3211x over previous
//
#include <hip/hip_runtime.h>

#define HW 4096
#define NC 256
#define NB 8
#define GN_EPS 1e-5f

typedef short bf16x8 __attribute__((ext_vector_type(8)));
typedef float f32x4 __attribute__((ext_vector_type(4)));
typedef float f32x16 __attribute__((ext_vector_type(16)));

#define MFMA16 __builtin_amdgcn_mfma_f32_16x16x32_bf16
#define MFMA32 __builtin_amdgcn_mfma_f32_32x32x16_bf16

// swizzle used only by qkv/outproj staging tiles
#define SWZ(row) ((((row) & 7) ^ (((row) >> 3) & 7)) << 4)

// q-scale folds 1/sqrt(256) AND log2(e) so softmax runs in base-2.
#define QSCALE 0.09016844f

__device__ __forceinline__ unsigned short f2bf(float f) {
  unsigned int u = __float_as_uint(f);
  u = (u + 0x7FFFu + ((u >> 16) & 1u)) >> 16;
  return (unsigned short)u;
}
__device__ __forceinline__ float bf2f(unsigned short h) {
  return __uint_as_float(((unsigned int)h) << 16);
}

__device__ __forceinline__ void gload16(const void* g, void* l) {
  __builtin_amdgcn_global_load_lds(
      (const __attribute__((address_space(1))) void*)g,
      (__attribute__((address_space(3))) void*)l, 16, 0, 0);
}

// ---------------------------------------------------------------- kernel 1
__global__ void gn_stats_kernel(const float* __restrict__ x,
                                const float* __restrict__ gnw,
                                const float* __restrict__ gnb,
                                float* __restrict__ s_arr,
                                float* __restrict__ t_arr) {
  int bg = blockIdx.x;
  int b = bg >> 5, g = bg & 31;
  const float4* base = (const float4*)(x + ((size_t)b * NC + g * 8) * HW);
  int tid = threadIdx.x;
  float s = 0.f, ss = 0.f;
  for (int it = 0; it < 32; ++it) {
    float4 v = base[tid + it * 256];
    s += v.x + v.y + v.z + v.w;
    ss += v.x * v.x + v.y * v.y + v.z * v.z + v.w * v.w;
  }
  for (int off = 32; off; off >>= 1) {
    s += __shfl_down(s, off);
    ss += __shfl_down(ss, off);
  }
  __shared__ float red[8];
  __shared__ float bc[2];
  int wave = tid >> 6, lane = tid & 63;
  if (lane == 0) { red[wave] = s; red[4 + wave] = ss; }
  __syncthreads();
  if (tid == 0) {
    float S = red[0] + red[1] + red[2] + red[3];
    float SS = red[4] + red[5] + red[6] + red[7];
    float mean = S * (1.f / 32768.f);
    float var = SS * (1.f / 32768.f) - mean * mean;
    bc[0] = mean;
    bc[1] = rsqrtf(var + GN_EPS);
  }
  __syncthreads();
  if (tid < 8) {
    int c = g * 8 + tid;
    float sv = bc[1] * gnw[c];
    s_arr[b * NC + c] = sv;
    t_arr[b * NC + c] = gnb[c] - bc[0] * sv;
  }
}

// ---------------------------------------------------------------- kernel 2
// QKV GEMM. q -> qb[p][c] (scaled), k -> CHUNKED kc_[b][ch=c/8][p][e=c&7],
// v -> vb[p][c] (plain; transposed to chunks by kernel 3).
__global__ __launch_bounds__(256) void qkv_gemm_kernel(
    const float* __restrict__ x, const float* __restrict__ s_arr,
    const float* __restrict__ t_arr, const float* __restrict__ w,
    const float* __restrict__ bias, unsigned short* __restrict__ qb,
    unsigned short* __restrict__ kc_, unsigned short* __restrict__ vb) {
  int b = blockIdx.z;
  int p0 = blockIdx.x * 64;
  int o0 = blockIdx.y * 128;
  int tid = threadIdx.x;
  int wave = tid >> 6, lane = tid & 63;
  int l15 = lane & 15, q4 = lane >> 4;
  int wm = wave >> 1, wn = wave & 1;
  __shared__ unsigned short a_lds[64 * 64];
  __shared__ unsigned short b_lds[128 * 64];
  char* aB = (char*)a_lds;
  char* bB = (char*)b_lds;
  f32x4 acc[2][4];
  for (int i = 0; i < 2; ++i)
    for (int j = 0; j < 4; ++j) acc[i][j] = (f32x4){0.f, 0.f, 0.f, 0.f};

  for (int kc0 = 0; kc0 < 256; kc0 += 64) {
    __syncthreads();
    for (int it = 0; it < 4; ++it) {
      int idx = tid + it * 256;
      int c = idx >> 4, p4 = idx & 15;
      float4 xv = *(const float4*)(x + ((size_t)b * NC + kc0 + c) * HW + p0 + p4 * 4);
      float sc = s_arr[b * NC + kc0 + c];
      float tc = t_arr[b * NC + kc0 + c];
      float vals[4] = {xv.x, xv.y, xv.z, xv.w};
      for (int i = 0; i < 4; ++i) {
        int p = p4 * 4 + i;
        *(unsigned short*)(aB + ((p * 128 + c * 2) ^ SWZ(p))) =
            f2bf(vals[i] * sc + tc);
      }
    }
    for (int it = 0; it < 8; ++it) {
      int idx = tid + it * 256;
      int o = idx >> 4, c4 = idx & 15;
      float4 wv = *(const float4*)(w + (size_t)(o0 + o) * NC + kc0 + c4 * 4);
      ushort4 hv = make_ushort4(f2bf(wv.x), f2bf(wv.y), f2bf(wv.z), f2bf(wv.w));
      *(ushort4*)(bB + ((o * 128 + c4 * 8) ^ SWZ(o))) = hv;
    }
    __syncthreads();
    for (int kk = 0; kk < 2; ++kk) {
      bf16x8 af[2], bfv[4];
      for (int pb = 0; pb < 2; ++pb) {
        int row = wm * 32 + pb * 16 + l15;
        af[pb] = *(const bf16x8*)(aB + ((row * 128 + kk * 64 + q4 * 16) ^ SWZ(row)));
      }
      for (int ob = 0; ob < 4; ++ob) {
        int row = wn * 64 + ob * 16 + l15;
        bfv[ob] = *(const bf16x8*)(bB + ((row * 128 + kk * 64 + q4 * 16) ^ SWZ(row)));
      }
      for (int pb = 0; pb < 2; ++pb)
        for (int ob = 0; ob < 4; ++ob)
          acc[pb][ob] = MFMA16(af[pb], bfv[ob], acc[pb][ob], 0, 0, 0);
    }
  }
  for (int pb = 0; pb < 2; ++pb) {
    for (int ob = 0; ob < 4; ++ob) {
      int og = o0 + wn * 64 + ob * 16 + l15;
      int tsel = og >> 8, oc = og & 255;
      float bi = bias[og];
      for (int r = 0; r < 4; ++r) {
        int p = p0 + wm * 32 + pb * 16 + q4 * 4 + r;
        float val = acc[pb][ob][r] + bi;
        if (tsel == 0) {
          qb[((size_t)b * HW + p) * NC + oc] = f2bf(val * QSCALE);
        } else if (tsel == 1) {
          kc_[((size_t)(b * 32 + (oc >> 3)) * HW + p) * 8 + (oc & 7)] = f2bf(val);
        } else {
          vb[((size_t)b * HW + p) * NC + oc] = f2bf(val);
        }
      }
    }
  }
}

// ---------------------------------------------------------------- kernel 3
// vb[p][c] -> vc[b][jcg=p/8][c][e=p&7]  (chunked, flash-staging-ready)
__global__ void transpose_v_kernel(const unsigned short* __restrict__ vb,
                                   unsigned short* __restrict__ vc) {
  int b = blockIdx.z;
  int p0 = blockIdx.x * 64, c0 = blockIdx.y * 64;
  int tid = threadIdx.x;
  __shared__ unsigned short tl[64 * 64];  // [c][p] swizzled
  char* tB = (char*)tl;
  for (int rep = 0; rep < 2; ++rep) {
    int p = (tid >> 3) + rep * 32;
    int c8 = (tid & 7) * 8;
    uint4 raw = *(const uint4*)(vb + ((size_t)b * HW + p0 + p) * NC + c0 + c8);
    unsigned int rr[4] = {raw.x, raw.y, raw.z, raw.w};
    for (int i = 0; i < 4; ++i) {
      int c_a = c8 + i * 2, c_b = c8 + i * 2 + 1;
      *(unsigned short*)(tB + ((c_a * 128 + p * 2) ^ SWZ(c_a))) =
          (unsigned short)(rr[i] & 0xffffu);
      *(unsigned short*)(tB + ((c_b * 128 + p * 2) ^ SWZ(c_b))) =
          (unsigned short)(rr[i] >> 16);
    }
  }
  __syncthreads();
  for (int rep = 0; rep < 2; ++rep) {
    int c = (tid >> 3) + rep * 32;
    int jc8 = tid & 7;
    bf16x8 val = *(const bf16x8*)(tB + ((c * 128 + jc8 * 16) ^ SWZ(c)));
    *(bf16x8*)(vc + (((size_t)b * 512 + (p0 >> 3) + jc8) * 256 + c0 + c) * 8) = val;
  }
}

// ---------------------------------------------------------------- kernel 4
// Flash attention v5: 32x32x16 MFMA, swapped QK^T (P lane-local), in-register
// softmax + in-register P->PV A-frag assembly (shfl_xor 32). 4 waves x 32
// q-rows, j-tile 32, K/V both double-buffered via global_load_lds (64KB LDS,
// 2 blocks/CU -> each SIMD gets 2 waves from INDEPENDENT blocks). One barrier
// per step. j split in 2 halves; partials merged in outproj.
__global__ __launch_bounds__(256, 2) void flash_attn_kernel(
    const unsigned short* __restrict__ qb, const unsigned short* __restrict__ kc_,
    const unsigned short* __restrict__ vc, unsigned short* __restrict__ Oh0,
    unsigned short* __restrict__ Oh1, float* __restrict__ Lb) {
  int b = blockIdx.x & 7;           // batch -> XCD
  int qt = (blockIdx.x >> 3) & 31;  // 0..31 (128 q rows each)
  int half = blockIdx.x >> 8;       // 0..1
  int tid = threadIdx.x;
  int wave = tid >> 6, lane = tid & 63;
  int l31 = lane & 31;
  int hi = lane >> 5;

  __shared__ unsigned short k_lds[2][8192];  // [buf][ch=32][j=32][e=8] 16KB
  __shared__ unsigned short v_lds[2][8192];  // [buf][jc=4][c=256][e=8] 16KB

  const char* kcb = (const char*)(kc_ + (size_t)b * 32 * HW * 8);
  const char* vcb = (const char*)(vc + (size_t)b * 512 * NC * 8);

  // Q fragments: B-operand, lane holds Q[q=l31][k=kb*16+hi*8+e]
  bf16x8 qf[16];
  {
    const unsigned short* qrow =
        qb + ((size_t)b * HW + qt * 128 + wave * 32 + l31) * NC;
#pragma unroll
    for (int kb = 0; kb < 16; ++kb)
      qf[kb] = *(const bf16x8*)(qrow + kb * 16 + hi * 8);
  }

  f32x16 acc[8];
#pragma unroll
  for (int nb = 0; nb < 8; ++nb)
#pragma unroll
    for (int i = 0; i < 16; ++i) acc[nb][i] = 0.f;
  float m_r = -1e30f, l_r = 0.f;

  int j0b = half * 2048;

  // prologue: stage tile 0
#pragma unroll
  for (int i = 0; i < 4; ++i)
    gload16(kcb + (size_t)((tid >> 5) + i * 8) * 65536 + (size_t)(j0b + (tid & 31)) * 16,
            (char*)k_lds[0] + tid * 16 + i * 4096);
#pragma unroll
  for (int i = 0; i < 4; ++i)
    gload16(vcb + (size_t)((j0b >> 3) + i) * 4096 + tid * 16,
            (char*)v_lds[0] + tid * 16 + i * 4096);
  __syncthreads();

  for (int t = 0; t < 64; ++t) {
    int cur = t & 1;
    if (t < 63) {  // stage next tile into alt buffers (drained at end barrier)
      int j0 = j0b + (t + 1) * 32;
#pragma unroll
      for (int i = 0; i < 4; ++i)
        gload16(kcb + (size_t)((tid >> 5) + i * 8) * 65536 + (size_t)(j0 + (tid & 31)) * 16,
                (char*)k_lds[cur ^ 1] + tid * 16 + i * 4096);
#pragma unroll
      for (int i = 0; i < 4; ++i)
        gload16(vcb + (size_t)((j0 >> 3) + i) * 4096 + tid * 16,
                (char*)v_lds[cur ^ 1] + tid * 16 + i * 4096);
    }
    const char* kB = (const char*)k_lds[cur];
    const char* vB = (const char*)v_lds[cur];

    // S^T = K Q : lane holds S[j=(reg&3)+8*(reg>>2)+4*hi][q=l31]
    f32x16 p;
#pragma unroll
    for (int i = 0; i < 16; ++i) p[i] = 0.f;
    __builtin_amdgcn_s_setprio(1);
#pragma unroll
    for (int kb = 0; kb < 16; ++kb) {
      bf16x8 kf = *(const bf16x8*)(kB + (kb * 2 + hi) * 512 + l31 * 16);
      p = MFMA32(kf, qf[kb], p, 0, 0, 0);
    }
    __builtin_amdgcn_s_setprio(0);

    // in-register online softmax (q = l31 per lane; halves share q)
    float pmax = p[0];
#pragma unroll
    for (int i = 1; i < 16; ++i) pmax = fmaxf(pmax, p[i]);
    pmax = fmaxf(pmax, __shfl_xor(pmax, 32));
    if (!__all(pmax - m_r <= 12.0f)) {  // rare rescale (defer-max THR=12)
      float mn = fmaxf(m_r, pmax);
      float sf = exp2f(m_r - mn);
      m_r = mn;
      l_r *= sf;
#pragma unroll
      for (int reg = 0; reg < 16; ++reg) {
        float sfr = __shfl(sf, (reg & 3) + 8 * (reg >> 2) + 4 * hi);
#pragma unroll
        for (int nb = 0; nb < 8; ++nb) acc[nb][reg] *= sfr;
      }
    }
    float rs = 0.f;
#pragma unroll
    for (int i = 0; i < 16; ++i) {
      p[i] = exp2f(p[i] - m_r);
      rs += p[i];
    }
    rs += __shfl_xor(rs, 32);
    l_r += rs;

    // pack P to bf16 pairs; assemble PV A-frags in-register:
    // frag kb dword d needs pk[4kb + 2*hi + (d&1)] from half (d>>1).
    int pk[8];
#pragma unroll
    for (int i = 0; i < 8; ++i)
      pk[i] = (int)f2bf(p[2 * i]) | ((int)f2bf(p[2 * i + 1]) << 16);
    union PU { int w[4]; bf16x8 v; } pu[2];
#pragma unroll
    for (int kb = 0; kb < 2; ++kb) {
      int base = 4 * kb;
      int pushA = hi ? pk[base + 0] : pk[base + 2];
      int pushB = hi ? pk[base + 1] : pk[base + 3];
      int shA = __shfl_xor(pushA, 32);
      int shB = __shfl_xor(pushB, 32);
      pu[kb].w[0] = hi ? shA : pk[base + 0];
      pu[kb].w[1] = hi ? shB : pk[base + 1];
      pu[kb].w[2] = hi ? pk[base + 2] : shA;
      pu[kb].w[3] = hi ? pk[base + 3] : shB;
    }

    // O += P V : acc[nb] rows = q(regmap), cols c = nb*32 + l31
    __builtin_amdgcn_s_setprio(1);
#pragma unroll
    for (int nb = 0; nb < 8; ++nb) {
#pragma unroll
      for (int kb = 0; kb < 2; ++kb) {
        bf16x8 vf = *(const bf16x8*)(vB + (kb * 2 + hi) * 4096 +
                                     (nb * 32 + l31) * 16);
        acc[nb] = MFMA32(pu[kb].v, vf, acc[nb], 0, 0, 0);
      }
    }
    __builtin_amdgcn_s_setprio(0);
    __syncthreads();  // next tile landed; cur buffers free
  }

  // epilogue: normalize (l per q = l31 -> redistribute to reg-rows), store
  float linv = 1.f / l_r;
  unsigned short* Ohp = (half ? Oh1 : Oh0) +
                        ((size_t)b * HW + qt * 128 + wave * 32) * NC;
#pragma unroll
  for (int reg = 0; reg < 16; ++reg) {
    int row = (reg & 3) + 8 * (reg >> 2) + 4 * hi;
    float lr = __shfl(linv, row);
#pragma unroll
    for (int nb = 0; nb < 8; ++nb)
      Ohp[(size_t)row * NC + nb * 32 + l31] = f2bf(acc[nb][reg] * lr);
  }
  if (lane < 32) {
    float* Lp = Lb + (size_t)half * NB * HW;
    Lp[(size_t)b * HW + qt * 128 + wave * 32 + lane] = m_r + log2f(l_r);
  }
}

// ---------------------------------------------------------------- kernel 5
// out = out_w @ merged_att^T + out_b + x; partial-O merge fused into staging.
__global__ __launch_bounds__(256) void outproj_kernel(
    const float* __restrict__ ow, const float* __restrict__ obias,
    const unsigned short* __restrict__ Oh0, const unsigned short* __restrict__ Oh1,
    const float* __restrict__ Lb, const float* __restrict__ x,
    float* __restrict__ out) {
  int b = blockIdx.y;
  int p0 = blockIdx.x * 64;
  int tid = threadIdx.x;
  int wave = tid >> 6, lane = tid & 63;
  int l15 = lane & 15, q4 = lane >> 4;
  __shared__ unsigned short aw_lds[256 * 64];
  __shared__ unsigned short bt_lds[64 * 64];
  char* aB = (char*)aw_lds;
  char* bB = (char*)bt_lds;
  f32x4 acc[4][4];
  for (int i = 0; i < 4; ++i)
    for (int j = 0; j < 4; ++j) acc[i][j] = (f32x4){0.f, 0.f, 0.f, 0.f};

  for (int kc0 = 0; kc0 < 256; kc0 += 64) {
    __syncthreads();
    for (int it = 0; it < 16; ++it) {
      int idx = tid + it * 256;
      int o = idx >> 4, c4 = idx & 15;
      float4 wv = *(const float4*)(ow + (size_t)o * NC + kc0 + c4 * 4);
      ushort4 hv = make_ushort4(f2bf(wv.x), f2bf(wv.y), f2bf(wv.z), f2bf(wv.w));
      *(ushort4*)(aB + ((o * 128 + c4 * 8) ^ SWZ(o))) = hv;
    }
    for (int it = 0; it < 2; ++it) {
      int idx = tid + it * 256;
      int p = idx >> 3, c8i = idx & 7;
      int row = p0 + p;
      float L1 = Lb[(size_t)b * HW + row];
      float L2 = Lb[(size_t)(NB + b) * HW + row];
      float w1 = 1.f / (1.f + exp2f(L2 - L1));
      float w2 = 1.f - w1;
      const unsigned short* o1p = Oh0 + ((size_t)b * HW + row) * NC + kc0 + c8i * 8;
      const unsigned short* o2p = Oh1 + ((size_t)b * HW + row) * NC + kc0 + c8i * 8;
      uint4 ra = *(const uint4*)o1p;
      uint4 rb = *(const uint4*)o2p;
      unsigned int aw[4] = {ra.x, ra.y, ra.z, ra.w};
      unsigned int bw[4] = {rb.x, rb.y, rb.z, rb.w};
      unsigned int outw[4];
      for (int i = 0; i < 4; ++i) {
        float lo = w1 * bf2f((unsigned short)(aw[i] & 0xffffu)) +
                   w2 * bf2f((unsigned short)(bw[i] & 0xffffu));
        float hic = w1 * bf2f((unsigned short)(aw[i] >> 16)) +
                    w2 * bf2f((unsigned short)(bw[i] >> 16));
        outw[i] = (unsigned int)f2bf(lo) | ((unsigned int)f2bf(hic) << 16);
      }
      *(uint4*)(bB + ((p * 128 + c8i * 16) ^ SWZ(p))) =
          make_uint4(outw[0], outw[1], outw[2], outw[3]);
    }
    __syncthreads();
    for (int kk = 0; kk < 2; ++kk) {
      bf16x8 af[4], bfv[4];
      for (int obk = 0; obk < 4; ++obk) {
        int row = wave * 64 + obk * 16 + l15;
        af[obk] = *(const bf16x8*)(aB + ((row * 128 + kk * 64 + q4 * 16) ^ SWZ(row)));
      }
      for (int pb = 0; pb < 4; ++pb) {
        int row = pb * 16 + l15;
        bfv[pb] = *(const bf16x8*)(bB + ((row * 128 + kk * 64 + q4 * 16) ^ SWZ(row)));
      }
      for (int obk = 0; obk < 4; ++obk)
        for (int pb = 0; pb < 4; ++pb)
          acc[obk][pb] = MFMA16(af[obk], bfv[pb], acc[obk][pb], 0, 0, 0);
    }
  }
  for (int obk = 0; obk < 4; ++obk)
    for (int pb = 0; pb < 4; ++pb)
      for (int r = 0; r < 4; ++r) {
        int o = wave * 64 + obk * 16 + q4 * 4 + r;
        int p = p0 + pb * 16 + l15;
        size_t gi = ((size_t)b * NC + o) * HW + p;
        out[gi] = acc[obk][pb][r] + obias[o] + x[gi];
      }
}

// ---------------------------------------------------------------- launch
extern "C" void kernel_launch(void* const* d_in, const int* in_sizes, int n_in,
                              void* d_out, int out_size, void* d_ws, size_t ws_size,
                              hipStream_t stream) {
  (void)in_sizes; (void)n_in; (void)out_size; (void)ws_size;
  const float* x = (const float*)d_in[0];
  const float* gnw = (const float*)d_in[1];
  const float* gnb = (const float*)d_in[2];
  const float* qkvw = (const float*)d_in[3];
  const float* qkvb = (const float*)d_in[4];
  const float* ow = (const float*)d_in[5];
  const float* obias = (const float*)d_in[6];
  float* out = (float*)d_out;

  char* ws = (char*)d_ws;
  float* s_arr = (float*)ws;
  float* t_arr = s_arr + NB * NC;
  size_t tsz = (size_t)NB * HW * NC;  // 8M ushort = 16MB
  unsigned short* qb = (unsigned short*)(ws + 16384);
  unsigned short* kc_ = qb + tsz;
  unsigned short* vb = kc_ + tsz;      // plain V; reused as Oh0 after transpose
  unsigned short* vc = vb + tsz;
  unsigned short* Oh1 = vc + tsz;
  float* Lb = (float*)(Oh1 + tsz);     // 2*NB*HW f32 = 256KB
  unsigned short* Oh0 = vb;            // reuse

  hipLaunchKernelGGL(gn_stats_kernel, dim3(NB * 32), dim3(256), 0, stream,
                     x, gnw, gnb, s_arr, t_arr);
  hipLaunchKernelGGL(qkv_gemm_kernel, dim3(64, 6, NB), dim3(256), 0, stream,
                     x, s_arr, t_arr, qkvw, qkvb, qb, kc_, vb);
  hipLaunchKernelGGL(transpose_v_kernel, dim3(64, 4, NB), dim3(256), 0, stream,
                     vb, vc);
  hipLaunchKernelGGL(flash_attn_kernel, dim3(512), dim3(256), 0, stream,
                     qb, kc_, vc, Oh0, Oh1, Lb);
  hipLaunchKernelGGL(outproj_kernel, dim3(64, NB), dim3(256), 0, stream,
                     ow, obias, Oh0, Oh1, Lb, x, out);
}

// Round 6
// 239.929 us; speedup vs baseline: 1.4609x; 1.1059x over previous
//
#include <hip/hip_runtime.h>

#define HW 4096
#define NC 256
#define NB 8
#define GN_EPS 1e-5f

typedef short bf16x8 __attribute__((ext_vector_type(8)));
typedef float f32x4 __attribute__((ext_vector_type(4)));
typedef float f32x16 __attribute__((ext_vector_type(16)));

#define MFMA16 __builtin_amdgcn_mfma_f32_16x16x32_bf16
#define MFMA32 __builtin_amdgcn_mfma_f32_32x32x16_bf16

// swizzle used only by qkv/outproj staging tiles
#define SWZ(row) ((((row) & 7) ^ (((row) >> 3) & 7)) << 4)

// q-scale folds 1/sqrt(256) AND log2(e) so softmax runs in base-2.
#define QSCALE 0.09016844f

__device__ __forceinline__ unsigned short f2bf(float f) {
  unsigned int u = __float_as_uint(f);
  u = (u + 0x7FFFu + ((u >> 16) & 1u)) >> 16;
  return (unsigned short)u;
}
__device__ __forceinline__ float bf2f(unsigned short h) {
  return __uint_as_float(((unsigned int)h) << 16);
}

__device__ __forceinline__ void gload16(const void* g, void* l) {
  __builtin_amdgcn_global_load_lds(
      (const __attribute__((address_space(1))) void*)g,
      (__attribute__((address_space(3))) void*)l, 16, 0, 0);
}

// ---------------------------------------------------------------- kernel 1
__global__ void gn_stats_kernel(const float* __restrict__ x,
                                const float* __restrict__ gnw,
                                const float* __restrict__ gnb,
                                float* __restrict__ s_arr,
                                float* __restrict__ t_arr) {
  int bg = blockIdx.x;
  int b = bg >> 5, g = bg & 31;
  const float4* base = (const float4*)(x + ((size_t)b * NC + g * 8) * HW);
  int tid = threadIdx.x;
  float s = 0.f, ss = 0.f;
  for (int it = 0; it < 32; ++it) {
    float4 v = base[tid + it * 256];
    s += v.x + v.y + v.z + v.w;
    ss += v.x * v.x + v.y * v.y + v.z * v.z + v.w * v.w;
  }
  for (int off = 32; off; off >>= 1) {
    s += __shfl_down(s, off);
    ss += __shfl_down(ss, off);
  }
  __shared__ float red[8];
  __shared__ float bc[2];
  int wave = tid >> 6, lane = tid & 63;
  if (lane == 0) { red[wave] = s; red[4 + wave] = ss; }
  __syncthreads();
  if (tid == 0) {
    float S = red[0] + red[1] + red[2] + red[3];
    float SS = red[4] + red[5] + red[6] + red[7];
    float mean = S * (1.f / 32768.f);
    float var = SS * (1.f / 32768.f) - mean * mean;
    bc[0] = mean;
    bc[1] = rsqrtf(var + GN_EPS);
  }
  __syncthreads();
  if (tid < 8) {
    int c = g * 8 + tid;
    float sv = bc[1] * gnw[c];
    s_arr[b * NC + c] = sv;
    t_arr[b * NC + c] = gnb[c] - bc[0] * sv;
  }
}

// ---------------------------------------------------------------- kernel 2
// QKV GEMM. q -> qb[p][c] (scaled), k -> CHUNKED kc_[b][ch=c/8][p][e=c&7],
// v -> CHUNKED vc[b][jc=p/8][c][e=p&7] (direct; transpose kernel eliminated).
__global__ __launch_bounds__(256) void qkv_gemm_kernel(
    const float* __restrict__ x, const float* __restrict__ s_arr,
    const float* __restrict__ t_arr, const float* __restrict__ w,
    const float* __restrict__ bias, unsigned short* __restrict__ qb,
    unsigned short* __restrict__ kc_, unsigned short* __restrict__ vc) {
  int b = blockIdx.z;
  int p0 = blockIdx.x * 64;
  int o0 = blockIdx.y * 128;
  int tid = threadIdx.x;
  int wave = tid >> 6, lane = tid & 63;
  int l15 = lane & 15, q4 = lane >> 4;
  int wm = wave >> 1, wn = wave & 1;
  __shared__ unsigned short a_lds[64 * 64];
  __shared__ unsigned short b_lds[128 * 64];
  char* aB = (char*)a_lds;
  char* bB = (char*)b_lds;
  f32x4 acc[2][4];
  for (int i = 0; i < 2; ++i)
    for (int j = 0; j < 4; ++j) acc[i][j] = (f32x4){0.f, 0.f, 0.f, 0.f};

  for (int kc0 = 0; kc0 < 256; kc0 += 64) {
    __syncthreads();
    for (int it = 0; it < 4; ++it) {
      int idx = tid + it * 256;
      int c = idx >> 4, p4 = idx & 15;
      float4 xv = *(const float4*)(x + ((size_t)b * NC + kc0 + c) * HW + p0 + p4 * 4);
      float sc = s_arr[b * NC + kc0 + c];
      float tc = t_arr[b * NC + kc0 + c];
      float vals[4] = {xv.x, xv.y, xv.z, xv.w};
      for (int i = 0; i < 4; ++i) {
        int p = p4 * 4 + i;
        *(unsigned short*)(aB + ((p * 128 + c * 2) ^ SWZ(p))) =
            f2bf(vals[i] * sc + tc);
      }
    }
    for (int it = 0; it < 8; ++it) {
      int idx = tid + it * 256;
      int o = idx >> 4, c4 = idx & 15;
      float4 wv = *(const float4*)(w + (size_t)(o0 + o) * NC + kc0 + c4 * 4);
      ushort4 hv = make_ushort4(f2bf(wv.x), f2bf(wv.y), f2bf(wv.z), f2bf(wv.w));
      *(ushort4*)(bB + ((o * 128 + c4 * 8) ^ SWZ(o))) = hv;
    }
    __syncthreads();
    for (int kk = 0; kk < 2; ++kk) {
      bf16x8 af[2], bfv[4];
      for (int pb = 0; pb < 2; ++pb) {
        int row = wm * 32 + pb * 16 + l15;
        af[pb] = *(const bf16x8*)(aB + ((row * 128 + kk * 64 + q4 * 16) ^ SWZ(row)));
      }
      for (int ob = 0; ob < 4; ++ob) {
        int row = wn * 64 + ob * 16 + l15;
        bfv[ob] = *(const bf16x8*)(bB + ((row * 128 + kk * 64 + q4 * 16) ^ SWZ(row)));
      }
      for (int pb = 0; pb < 2; ++pb)
        for (int ob = 0; ob < 4; ++ob)
          acc[pb][ob] = MFMA16(af[pb], bfv[ob], acc[pb][ob], 0, 0, 0);
    }
  }
  for (int pb = 0; pb < 2; ++pb) {
    for (int ob = 0; ob < 4; ++ob) {
      int og = o0 + wn * 64 + ob * 16 + l15;
      int tsel = og >> 8, oc = og & 255;
      float bi = bias[og];
      if (tsel == 2) {  // V: 4 consecutive p share a chunk -> one ushort4 store
        int p = p0 + wm * 32 + pb * 16 + q4 * 4;
        ushort4 pk4 = make_ushort4(
            f2bf(acc[pb][ob][0] + bi), f2bf(acc[pb][ob][1] + bi),
            f2bf(acc[pb][ob][2] + bi), f2bf(acc[pb][ob][3] + bi));
        *(ushort4*)(vc + (((size_t)b * 512 + (p >> 3)) * 256 + oc) * 8 + (p & 7)) =
            pk4;
      } else {
        for (int r = 0; r < 4; ++r) {
          int p = p0 + wm * 32 + pb * 16 + q4 * 4 + r;
          float val = acc[pb][ob][r] + bi;
          if (tsel == 0) {
            qb[((size_t)b * HW + p) * NC + oc] = f2bf(val * QSCALE);
          } else {
            kc_[((size_t)(b * 32 + (oc >> 3)) * HW + p) * 8 + (oc & 7)] = f2bf(val);
          }
        }
      }
    }
  }
}

// ---------------------------------------------------------------- kernel 4
// Flash attention v6: as v5 (32x32x16 swapped QK^T, lane-local P, reg-only
// P->A assembly, K/V dbuf via global_load_lds, 1 barrier/step) with VALU trim:
// cvt_pk bf16 pack, tree reductions, persistent staging pointers, native exp2.
__global__ __launch_bounds__(256, 2) void flash_attn_kernel(
    const unsigned short* __restrict__ qb, const unsigned short* __restrict__ kc_,
    const unsigned short* __restrict__ vc, unsigned short* __restrict__ Oh0,
    unsigned short* __restrict__ Oh1, float* __restrict__ Lb) {
  int b = blockIdx.x & 7;           // batch -> XCD
  int qt = (blockIdx.x >> 3) & 31;  // q rows qt*128
  int half = blockIdx.x >> 8;       // 0..1 (j halves)
  int tid = threadIdx.x;
  int wave = tid >> 6, lane = tid & 63;
  int l31 = lane & 31;
  int hi = lane >> 5;

  __shared__ unsigned short k_lds[2][8192];  // [buf][ch=32][j=32][e=8]
  __shared__ unsigned short v_lds[2][8192];  // [buf][jc=4][c=256][e=8]

  int j0b = half * 2048;

  // persistent per-lane staging pointers, incremented each step
  const char* kp[4];
  const char* vp[4];
  {
    const char* kcb = (const char*)(kc_ + (size_t)b * 32 * HW * 8);
    const char* vcb = (const char*)(vc + (size_t)b * 512 * NC * 8);
#pragma unroll
    for (int i = 0; i < 4; ++i) {
      kp[i] = kcb + (size_t)((tid >> 5) + i * 8) * 65536 +
              (size_t)(j0b + (tid & 31)) * 16;
      vp[i] = vcb + (size_t)((j0b >> 3) + i) * 4096 + tid * 16;
    }
  }

  // Q fragments: B-operand, lane holds Q[q=l31][k=kb*16+hi*8+e]
  bf16x8 qf[16];
  {
    const unsigned short* qrow =
        qb + ((size_t)b * HW + qt * 128 + wave * 32 + l31) * NC;
#pragma unroll
    for (int kb = 0; kb < 16; ++kb)
      qf[kb] = *(const bf16x8*)(qrow + kb * 16 + hi * 8);
  }

  f32x16 acc[8];
#pragma unroll
  for (int nb = 0; nb < 8; ++nb)
#pragma unroll
    for (int i = 0; i < 16; ++i) acc[nb][i] = 0.f;
  float m_r = -1e30f, l_r = 0.f;

  // prologue: stage tile 0
#pragma unroll
  for (int i = 0; i < 4; ++i)
    gload16(kp[i], (char*)k_lds[0] + tid * 16 + i * 4096);
#pragma unroll
  for (int i = 0; i < 4; ++i)
    gload16(vp[i], (char*)v_lds[0] + tid * 16 + i * 4096);
  __syncthreads();

  for (int t = 0; t < 64; ++t) {
    int cur = t & 1;
    if (t < 63) {  // stage next tile (drained at end-of-step barrier)
#pragma unroll
      for (int i = 0; i < 4; ++i) {
        kp[i] += 512;
        gload16(kp[i], (char*)k_lds[cur ^ 1] + tid * 16 + i * 4096);
      }
#pragma unroll
      for (int i = 0; i < 4; ++i) {
        vp[i] += 16384;
        gload16(vp[i], (char*)v_lds[cur ^ 1] + tid * 16 + i * 4096);
      }
    }
    const char* kB = (const char*)k_lds[cur];
    const char* vB = (const char*)v_lds[cur];

    // S^T = K Q : lane holds S[j=(reg&3)+8*(reg>>2)+4*hi][q=l31]
    f32x16 p;
#pragma unroll
    for (int i = 0; i < 16; ++i) p[i] = 0.f;
    __builtin_amdgcn_s_setprio(1);
#pragma unroll
    for (int kb = 0; kb < 16; ++kb) {
      bf16x8 kf = *(const bf16x8*)(kB + (kb * 2 + hi) * 512 + l31 * 16);
      p = MFMA32(kf, qf[kb], p, 0, 0, 0);
    }
    __builtin_amdgcn_s_setprio(0);

    // tree max (depth 4) + cross-half swap
    float pmax;
    {
      float t0 = fmaxf(p[0], p[1]), t1 = fmaxf(p[2], p[3]);
      float t2 = fmaxf(p[4], p[5]), t3 = fmaxf(p[6], p[7]);
      float t4 = fmaxf(p[8], p[9]), t5 = fmaxf(p[10], p[11]);
      float t6 = fmaxf(p[12], p[13]), t7 = fmaxf(p[14], p[15]);
      float u0 = fmaxf(t0, t1), u1 = fmaxf(t2, t3);
      float u2 = fmaxf(t4, t5), u3 = fmaxf(t6, t7);
      pmax = fmaxf(fmaxf(u0, u1), fmaxf(u2, u3));
    }
    pmax = fmaxf(pmax, __shfl_xor(pmax, 32));
    if (!__all(pmax - m_r <= 12.0f)) {  // rare rescale (defer-max THR=12)
      float mn = fmaxf(m_r, pmax);
      float sf = exp2f(m_r - mn);
      m_r = mn;
      l_r *= sf;
#pragma unroll
      for (int reg = 0; reg < 16; ++reg) {
        float sfr = __shfl(sf, (reg & 3) + 8 * (reg >> 2) + 4 * hi);
#pragma unroll
        for (int nb = 0; nb < 8; ++nb) acc[nb][reg] *= sfr;
      }
    }
#pragma unroll
    for (int i = 0; i < 16; ++i) p[i] = __builtin_amdgcn_exp2f(p[i] - m_r);
    float rs;
    {
      float t0 = p[0] + p[1], t1 = p[2] + p[3];
      float t2 = p[4] + p[5], t3 = p[6] + p[7];
      float t4 = p[8] + p[9], t5 = p[10] + p[11];
      float t6 = p[12] + p[13], t7 = p[14] + p[15];
      float u0 = t0 + t1, u1 = t2 + t3, u2 = t4 + t5, u3 = t6 + t7;
      rs = (u0 + u1) + (u2 + u3);
    }
    rs += __shfl_xor(rs, 32);
    l_r += rs;

    // pack P to bf16 pairs via v_cvt_pk_bf16_f32 (T12), then assemble PV
    // A-frags in-register: frag kb dword d needs pk[4kb+2*hi+(d&1)] from
    // half (d>>1).
    int pk[8];
#pragma unroll
    for (int i = 0; i < 8; ++i) {
      int r;
      asm("v_cvt_pk_bf16_f32 %0, %1, %2"
          : "=v"(r)
          : "v"(p[2 * i]), "v"(p[2 * i + 1]));
      pk[i] = r;
    }
    union PU { int w[4]; bf16x8 v; } pu[2];
#pragma unroll
    for (int kb = 0; kb < 2; ++kb) {
      int base = 4 * kb;
      int pushA = hi ? pk[base + 0] : pk[base + 2];
      int pushB = hi ? pk[base + 1] : pk[base + 3];
      int shA = __shfl_xor(pushA, 32);
      int shB = __shfl_xor(pushB, 32);
      pu[kb].w[0] = hi ? shA : pk[base + 0];
      pu[kb].w[1] = hi ? shB : pk[base + 1];
      pu[kb].w[2] = hi ? pk[base + 2] : shA;
      pu[kb].w[3] = hi ? pk[base + 3] : shB;
    }

    // O += P V
    __builtin_amdgcn_s_setprio(1);
#pragma unroll
    for (int nb = 0; nb < 8; ++nb) {
#pragma unroll
      for (int kb = 0; kb < 2; ++kb) {
        bf16x8 vf = *(const bf16x8*)(vB + (kb * 2 + hi) * 4096 +
                                     (nb * 32 + l31) * 16);
        acc[nb] = MFMA32(pu[kb].v, vf, acc[nb], 0, 0, 0);
      }
    }
    __builtin_amdgcn_s_setprio(0);
    __syncthreads();  // next tile landed; cur buffers free
  }

  // epilogue: normalize and store partial O + L
  float linv = 1.f / l_r;
  unsigned short* Ohp = (half ? Oh1 : Oh0) +
                        ((size_t)b * HW + qt * 128 + wave * 32) * NC;
#pragma unroll
  for (int reg = 0; reg < 16; ++reg) {
    int row = (reg & 3) + 8 * (reg >> 2) + 4 * hi;
    float lr = __shfl(linv, row);
#pragma unroll
    for (int nb = 0; nb < 8; ++nb)
      Ohp[(size_t)row * NC + nb * 32 + l31] = f2bf(acc[nb][reg] * lr);
  }
  if (lane < 32) {
    float* Lp = Lb + (size_t)half * NB * HW;
    Lp[(size_t)b * HW + qt * 128 + wave * 32 + lane] = m_r + log2f(l_r);
  }
}

// ---------------------------------------------------------------- kernel 5
// out = out_w @ merged_att^T + out_b + x; partial-O merge fused into staging.
__global__ __launch_bounds__(256) void outproj_kernel(
    const float* __restrict__ ow, const float* __restrict__ obias,
    const unsigned short* __restrict__ Oh0, const unsigned short* __restrict__ Oh1,
    const float* __restrict__ Lb, const float* __restrict__ x,
    float* __restrict__ out) {
  int b = blockIdx.y;
  int p0 = blockIdx.x * 64;
  int tid = threadIdx.x;
  int wave = tid >> 6, lane = tid & 63;
  int l15 = lane & 15, q4 = lane >> 4;
  __shared__ unsigned short aw_lds[256 * 64];
  __shared__ unsigned short bt_lds[64 * 64];
  char* aB = (char*)aw_lds;
  char* bB = (char*)bt_lds;
  f32x4 acc[4][4];
  for (int i = 0; i < 4; ++i)
    for (int j = 0; j < 4; ++j) acc[i][j] = (f32x4){0.f, 0.f, 0.f, 0.f};

  for (int kc0 = 0; kc0 < 256; kc0 += 64) {
    __syncthreads();
    for (int it = 0; it < 16; ++it) {
      int idx = tid + it * 256;
      int o = idx >> 4, c4 = idx & 15;
      float4 wv = *(const float4*)(ow + (size_t)o * NC + kc0 + c4 * 4);
      ushort4 hv = make_ushort4(f2bf(wv.x), f2bf(wv.y), f2bf(wv.z), f2bf(wv.w));
      *(ushort4*)(aB + ((o * 128 + c4 * 8) ^ SWZ(o))) = hv;
    }
    for (int it = 0; it < 2; ++it) {
      int idx = tid + it * 256;
      int p = idx >> 3, c8i = idx & 7;
      int row = p0 + p;
      float L1 = Lb[(size_t)b * HW + row];
      float L2 = Lb[(size_t)(NB + b) * HW + row];
      float w1 = 1.f / (1.f + exp2f(L2 - L1));
      float w2 = 1.f - w1;
      const unsigned short* o1p = Oh0 + ((size_t)b * HW + row) * NC + kc0 + c8i * 8;
      const unsigned short* o2p = Oh1 + ((size_t)b * HW + row) * NC + kc0 + c8i * 8;
      uint4 ra = *(const uint4*)o1p;
      uint4 rb = *(const uint4*)o2p;
      unsigned int aw[4] = {ra.x, ra.y, ra.z, ra.w};
      unsigned int bw[4] = {rb.x, rb.y, rb.z, rb.w};
      unsigned int outw[4];
      for (int i = 0; i < 4; ++i) {
        float lo = w1 * bf2f((unsigned short)(aw[i] & 0xffffu)) +
                   w2 * bf2f((unsigned short)(bw[i] & 0xffffu));
        float hic = w1 * bf2f((unsigned short)(aw[i] >> 16)) +
                    w2 * bf2f((unsigned short)(bw[i] >> 16));
        outw[i] = (unsigned int)f2bf(lo) | ((unsigned int)f2bf(hic) << 16);
      }
      *(uint4*)(bB + ((p * 128 + c8i * 16) ^ SWZ(p))) =
          make_uint4(outw[0], outw[1], outw[2], outw[3]);
    }
    __syncthreads();
    for (int kk = 0; kk < 2; ++kk) {
      bf16x8 af[4], bfv[4];
      for (int obk = 0; obk < 4; ++obk) {
        int row = wave * 64 + obk * 16 + l15;
        af[obk] = *(const bf16x8*)(aB + ((row * 128 + kk * 64 + q4 * 16) ^ SWZ(row)));
      }
      for (int pb = 0; pb < 4; ++pb) {
        int row = pb * 16 + l15;
        bfv[pb] = *(const bf16x8*)(bB + ((row * 128 + kk * 64 + q4 * 16) ^ SWZ(row)));
      }
      for (int obk = 0; obk < 4; ++obk)
        for (int pb = 0; pb < 4; ++pb)
          acc[obk][pb] = MFMA16(af[obk], bfv[pb], acc[obk][pb], 0, 0, 0);
    }
  }
  for (int obk = 0; obk < 4; ++obk)
    for (int pb = 0; pb < 4; ++pb)
      for (int r = 0; r < 4; ++r) {
        int o = wave * 64 + obk * 16 + q4 * 4 + r;
        int p = p0 + pb * 16 + l15;
        size_t gi = ((size_t)b * NC + o) * HW + p;
        out[gi] = acc[obk][pb][r] + obias[o] + x[gi];
      }
}

// ---------------------------------------------------------------- launch
extern "C" void kernel_launch(void* const* d_in, const int* in_sizes, int n_in,
                              void* d_out, int out_size, void* d_ws, size_t ws_size,
                              hipStream_t stream) {
  (void)in_sizes; (void)n_in; (void)out_size; (void)ws_size;
  const float* x = (const float*)d_in[0];
  const float* gnw = (const float*)d_in[1];
  const float* gnb = (const float*)d_in[2];
  const float* qkvw = (const float*)d_in[3];
  const float* qkvb = (const float*)d_in[4];
  const float* ow = (const float*)d_in[5];
  const float* obias = (const float*)d_in[6];
  float* out = (float*)d_out;

  char* ws = (char*)d_ws;
  float* s_arr = (float*)ws;
  float* t_arr = s_arr + NB * NC;
  size_t tsz = (size_t)NB * HW * NC;  // 8M ushort = 16MB
  unsigned short* qb = (unsigned short*)(ws + 16384);
  unsigned short* kc_ = qb + tsz;
  unsigned short* Oh0 = kc_ + tsz;
  unsigned short* vc = Oh0 + tsz;
  unsigned short* Oh1 = vc + tsz;
  float* Lb = (float*)(Oh1 + tsz);  // 2*NB*HW f32 = 256KB

  hipLaunchKernelGGL(gn_stats_kernel, dim3(NB * 32), dim3(256), 0, stream,
                     x, gnw, gnb, s_arr, t_arr);
  hipLaunchKernelGGL(qkv_gemm_kernel, dim3(64, 6, NB), dim3(256), 0, stream,
                     x, s_arr, t_arr, qkvw, qkvb, qb, kc_, vc);
  hipLaunchKernelGGL(flash_attn_kernel, dim3(512), dim3(256), 0, stream,
                     qb, kc_, vc, Oh0, Oh1, Lb);
  hipLaunchKernelGGL(outproj_kernel, dim3(64, NB), dim3(256), 0, stream,
                     ow, obias, Oh0, Oh1, Lb, x, out);
}

// Round 7
// 208.129 us; speedup vs baseline: 1.6841x; 1.1528x over previous
//
#include <hip/hip_runtime.h>

#define HW 4096
#define NC 256
#define NB 8
#define GN_EPS 1e-5f

typedef short bf16x8 __attribute__((ext_vector_type(8)));
typedef float f32x4 __attribute__((ext_vector_type(4)));
typedef float f32x16 __attribute__((ext_vector_type(16)));

#define MFMA16 __builtin_amdgcn_mfma_f32_16x16x32_bf16
#define MFMA32 __builtin_amdgcn_mfma_f32_32x32x16_bf16

// XOR swizzle for [row][64-col] bf16 LDS tiles (128B rows)
#define SWZ(row) ((((row) & 7) ^ (((row) >> 3) & 7)) << 4)

// q-scale folds 1/sqrt(256) AND log2(e) so softmax runs in base-2.
#define QSCALE 0.09016844f

__device__ __forceinline__ unsigned short f2bf(float f) {
  unsigned int u = __float_as_uint(f);
  u = (u + 0x7FFFu + ((u >> 16) & 1u)) >> 16;
  return (unsigned short)u;
}
__device__ __forceinline__ float bf2f(unsigned short h) {
  return __uint_as_float(((unsigned int)h) << 16);
}

__device__ __forceinline__ void gload16(const void* g, void* l) {
  __builtin_amdgcn_global_load_lds(
      (const __attribute__((address_space(1))) void*)g,
      (__attribute__((address_space(3))) void*)l, 16, 0, 0);
}

// ---------------------------------------------------------------- kernel 1
__global__ void gn_stats_kernel(const float* __restrict__ x,
                                const float* __restrict__ gnw,
                                const float* __restrict__ gnb,
                                float* __restrict__ s_arr,
                                float* __restrict__ t_arr) {
  int bg = blockIdx.x;
  int b = bg >> 5, g = bg & 31;
  const float4* base = (const float4*)(x + ((size_t)b * NC + g * 8) * HW);
  int tid = threadIdx.x;
  float s = 0.f, ss = 0.f;
  for (int it = 0; it < 32; ++it) {
    float4 v = base[tid + it * 256];
    s += v.x + v.y + v.z + v.w;
    ss += v.x * v.x + v.y * v.y + v.z * v.z + v.w * v.w;
  }
  for (int off = 32; off; off >>= 1) {
    s += __shfl_down(s, off);
    ss += __shfl_down(ss, off);
  }
  __shared__ float red[8];
  __shared__ float bc[2];
  int wave = tid >> 6, lane = tid & 63;
  if (lane == 0) { red[wave] = s; red[4 + wave] = ss; }
  __syncthreads();
  if (tid == 0) {
    float S = red[0] + red[1] + red[2] + red[3];
    float SS = red[4] + red[5] + red[6] + red[7];
    float mean = S * (1.f / 32768.f);
    float var = SS * (1.f / 32768.f) - mean * mean;
    bc[0] = mean;
    bc[1] = rsqrtf(var + GN_EPS);
  }
  __syncthreads();
  if (tid < 8) {
    int c = g * 8 + tid;
    float sv = bc[1] * gnw[c];
    s_arr[b * NC + c] = sv;
    t_arr[b * NC + c] = gnb[c] - bc[0] * sv;
  }
}

// ---------------------------------------------------------------- kernel 1b
// Convert qkv_w (768x256) and out_w (256x256) fp32 -> bf16 into one buffer:
// wb[0..196607] = qkv_w, wb[196608..262143] = out_w.
__global__ void wconv_kernel(const float* __restrict__ qkvw,
                             const float* __restrict__ ow,
                             unsigned short* __restrict__ wb) {
  int i = blockIdx.x * 256 + threadIdx.x;  // 0..32767
  int off = i * 8;
  const float* src = (i < 24576) ? (qkvw + off) : (ow + (off - 196608));
  float4 a = *(const float4*)src;
  float4 c = *(const float4*)(src + 4);
  *(ushort4*)(wb + off) =
      make_ushort4(f2bf(a.x), f2bf(a.y), f2bf(a.z), f2bf(a.w));
  *(ushort4*)(wb + off + 4) =
      make_ushort4(f2bf(c.x), f2bf(c.y), f2bf(c.z), f2bf(c.w));
}

// ---------------------------------------------------------------- kernel 1c
// GN-apply + transpose + bf16: x[b][c][p] fp32 -> xt[b][p][c] bf16 (once).
__global__ __launch_bounds__(256) void gn_apply_kernel(
    const float* __restrict__ x, const float* __restrict__ s_arr,
    const float* __restrict__ t_arr, unsigned short* __restrict__ xt) {
  int b = blockIdx.z;
  int p0 = blockIdx.x * 64, c0 = blockIdx.y * 64;
  int tid = threadIdx.x;
  __shared__ unsigned short tl[64 * 64];  // [p][c] swizzled
  char* tB = (char*)tl;
  int cl = tid >> 4, p4 = tid & 15;
#pragma unroll
  for (int rep = 0; rep < 4; ++rep) {
    int c = cl + rep * 16;
    float4 xv = *(const float4*)(x + ((size_t)b * NC + c0 + c) * HW + p0 + p4 * 4);
    float sc = s_arr[b * NC + c0 + c];
    float tc = t_arr[b * NC + c0 + c];
    float vals[4] = {xv.x, xv.y, xv.z, xv.w};
#pragma unroll
    for (int i = 0; i < 4; ++i) {
      int p = p4 * 4 + i;
      *(unsigned short*)(tB + ((p * 128 + c * 2) ^ SWZ(p))) =
          f2bf(vals[i] * sc + tc);
    }
  }
  __syncthreads();
#pragma unroll
  for (int rep = 0; rep < 2; ++rep) {
    int p = (tid >> 3) + rep * 32;
    int c8 = (tid & 7) * 8;
    bf16x8 v = *(const bf16x8*)(tB + ((p * 128 + c8 * 2) ^ SWZ(p)));
    *(bf16x8*)(xt + ((size_t)b * HW + p0 + p) * NC + c0 + c8) = v;
  }
}

// ---------------------------------------------------------------- kernel 2
// QKV GEMM v2: A (xt) and B (wb, bf16) both staged via global_load_lds with
// pre-swizzled global sources; double-buffered K-chunks, 1 barrier/chunk.
// q -> qb[p][c] (scaled), k -> kc_[b][ch=c/8][p][e], v -> vc[b][jc=p/8][c][e].
__global__ __launch_bounds__(256) void qkv_gemm_kernel(
    const unsigned short* __restrict__ xt, const unsigned short* __restrict__ wb,
    const float* __restrict__ bias, unsigned short* __restrict__ qb,
    unsigned short* __restrict__ kc_, unsigned short* __restrict__ vc) {
  int b = blockIdx.z;
  int p0 = blockIdx.x * 64;
  int o0 = blockIdx.y * 128;
  int tid = threadIdx.x;
  int wave = tid >> 6, lane = tid & 63;
  int l15 = lane & 15, q4 = lane >> 4;
  int wm = wave >> 1, wn = wave & 1;
  __shared__ unsigned short a_lds[2][64 * 64];   // [p][c] swizzled
  __shared__ unsigned short b_lds[2][128 * 64];  // [o][c] swizzled

  const char* xtb = (const char*)(xt + ((size_t)b * HW + p0) * NC);
  const char* wbb = (const char*)wb + o0 * 512;
  unsigned int asrc[2], bsrc[4];
#pragma unroll
  for (int i = 0; i < 2; ++i) {
    int dk = wave * 2048 + i * 1024 + lane * 16;
    int row = dk >> 7;
    asrc[i] = row * 512 + ((dk & 127) ^ SWZ(row));
  }
#pragma unroll
  for (int i = 0; i < 4; ++i) {
    int dk = wave * 4096 + i * 1024 + lane * 16;
    int row = dk >> 7;
    bsrc[i] = row * 512 + ((dk & 127) ^ SWZ(row));
  }

  f32x4 acc[2][4];
#pragma unroll
  for (int i = 0; i < 2; ++i)
#pragma unroll
    for (int j = 0; j < 4; ++j) acc[i][j] = (f32x4){0.f, 0.f, 0.f, 0.f};

  // prologue: stage chunk 0
#pragma unroll
  for (int i = 0; i < 2; ++i)
    gload16(xtb + asrc[i], (char*)a_lds[0] + wave * 2048 + i * 1024 + lane * 16);
#pragma unroll
  for (int i = 0; i < 4; ++i)
    gload16(wbb + bsrc[i], (char*)b_lds[0] + wave * 4096 + i * 1024 + lane * 16);
  __syncthreads();

  for (int kc = 0; kc < 4; ++kc) {
    int cur = kc & 1;
    if (kc < 3) {
      int koff = (kc + 1) * 128;  // byte offset of next 64-c chunk
#pragma unroll
      for (int i = 0; i < 2; ++i)
        gload16(xtb + asrc[i] + koff,
                (char*)a_lds[cur ^ 1] + wave * 2048 + i * 1024 + lane * 16);
#pragma unroll
      for (int i = 0; i < 4; ++i)
        gload16(wbb + bsrc[i] + koff,
                (char*)b_lds[cur ^ 1] + wave * 4096 + i * 1024 + lane * 16);
    }
    const char* aB = (const char*)a_lds[cur];
    const char* bB = (const char*)b_lds[cur];
#pragma unroll
    for (int kk = 0; kk < 2; ++kk) {
      bf16x8 af[2], bfv[4];
#pragma unroll
      for (int pb = 0; pb < 2; ++pb) {
        int row = wm * 32 + pb * 16 + l15;
        af[pb] = *(const bf16x8*)(aB + ((row * 128 + kk * 64 + q4 * 16) ^ SWZ(row)));
      }
#pragma unroll
      for (int ob = 0; ob < 4; ++ob) {
        int row = wn * 64 + ob * 16 + l15;
        bfv[ob] = *(const bf16x8*)(bB + ((row * 128 + kk * 64 + q4 * 16) ^ SWZ(row)));
      }
#pragma unroll
      for (int pb = 0; pb < 2; ++pb)
#pragma unroll
        for (int ob = 0; ob < 4; ++ob)
          acc[pb][ob] = MFMA16(af[pb], bfv[ob], acc[pb][ob], 0, 0, 0);
    }
    __syncthreads();
  }

  for (int pb = 0; pb < 2; ++pb) {
    for (int ob = 0; ob < 4; ++ob) {
      int og = o0 + wn * 64 + ob * 16 + l15;
      int tsel = og >> 8, oc = og & 255;
      float bi = bias[og];
      if (tsel == 2) {  // V: 4 consecutive p share a chunk -> one ushort4 store
        int p = p0 + wm * 32 + pb * 16 + q4 * 4;
        ushort4 pk4 = make_ushort4(
            f2bf(acc[pb][ob][0] + bi), f2bf(acc[pb][ob][1] + bi),
            f2bf(acc[pb][ob][2] + bi), f2bf(acc[pb][ob][3] + bi));
        *(ushort4*)(vc + (((size_t)b * 512 + (p >> 3)) * 256 + oc) * 8 + (p & 7)) =
            pk4;
      } else {
        for (int r = 0; r < 4; ++r) {
          int p = p0 + wm * 32 + pb * 16 + q4 * 4 + r;
          float val = acc[pb][ob][r] + bi;
          if (tsel == 0) {
            qb[((size_t)b * HW + p) * NC + oc] = f2bf(val * QSCALE);
          } else {
            kc_[((size_t)(b * 32 + (oc >> 3)) * HW + p) * 8 + (oc & 7)] = f2bf(val);
          }
        }
      }
    }
  }
}

// ---------------------------------------------------------------- kernel 4
// Flash attention v6 (FROZEN from round 6).
__global__ __launch_bounds__(256, 2) void flash_attn_kernel(
    const unsigned short* __restrict__ qb, const unsigned short* __restrict__ kc_,
    const unsigned short* __restrict__ vc, unsigned short* __restrict__ Oh0,
    unsigned short* __restrict__ Oh1, float* __restrict__ Lb) {
  int b = blockIdx.x & 7;           // batch -> XCD
  int qt = (blockIdx.x >> 3) & 31;  // q rows qt*128
  int half = blockIdx.x >> 8;       // 0..1 (j halves)
  int tid = threadIdx.x;
  int wave = tid >> 6, lane = tid & 63;
  int l31 = lane & 31;
  int hi = lane >> 5;

  __shared__ unsigned short k_lds[2][8192];  // [buf][ch=32][j=32][e=8]
  __shared__ unsigned short v_lds[2][8192];  // [buf][jc=4][c=256][e=8]

  int j0b = half * 2048;

  const char* kp[4];
  const char* vp[4];
  {
    const char* kcb = (const char*)(kc_ + (size_t)b * 32 * HW * 8);
    const char* vcb = (const char*)(vc + (size_t)b * 512 * NC * 8);
#pragma unroll
    for (int i = 0; i < 4; ++i) {
      kp[i] = kcb + (size_t)((tid >> 5) + i * 8) * 65536 +
              (size_t)(j0b + (tid & 31)) * 16;
      vp[i] = vcb + (size_t)((j0b >> 3) + i) * 4096 + tid * 16;
    }
  }

  bf16x8 qf[16];
  {
    const unsigned short* qrow =
        qb + ((size_t)b * HW + qt * 128 + wave * 32 + l31) * NC;
#pragma unroll
    for (int kb = 0; kb < 16; ++kb)
      qf[kb] = *(const bf16x8*)(qrow + kb * 16 + hi * 8);
  }

  f32x16 acc[8];
#pragma unroll
  for (int nb = 0; nb < 8; ++nb)
#pragma unroll
    for (int i = 0; i < 16; ++i) acc[nb][i] = 0.f;
  float m_r = -1e30f, l_r = 0.f;

#pragma unroll
  for (int i = 0; i < 4; ++i)
    gload16(kp[i], (char*)k_lds[0] + tid * 16 + i * 4096);
#pragma unroll
  for (int i = 0; i < 4; ++i)
    gload16(vp[i], (char*)v_lds[0] + tid * 16 + i * 4096);
  __syncthreads();

  for (int t = 0; t < 64; ++t) {
    int cur = t & 1;
    if (t < 63) {
#pragma unroll
      for (int i = 0; i < 4; ++i) {
        kp[i] += 512;
        gload16(kp[i], (char*)k_lds[cur ^ 1] + tid * 16 + i * 4096);
      }
#pragma unroll
      for (int i = 0; i < 4; ++i) {
        vp[i] += 16384;
        gload16(vp[i], (char*)v_lds[cur ^ 1] + tid * 16 + i * 4096);
      }
    }
    const char* kB = (const char*)k_lds[cur];
    const char* vB = (const char*)v_lds[cur];

    f32x16 p;
#pragma unroll
    for (int i = 0; i < 16; ++i) p[i] = 0.f;
    __builtin_amdgcn_s_setprio(1);
#pragma unroll
    for (int kb = 0; kb < 16; ++kb) {
      bf16x8 kf = *(const bf16x8*)(kB + (kb * 2 + hi) * 512 + l31 * 16);
      p = MFMA32(kf, qf[kb], p, 0, 0, 0);
    }
    __builtin_amdgcn_s_setprio(0);

    float pmax;
    {
      float t0 = fmaxf(p[0], p[1]), t1 = fmaxf(p[2], p[3]);
      float t2 = fmaxf(p[4], p[5]), t3 = fmaxf(p[6], p[7]);
      float t4 = fmaxf(p[8], p[9]), t5 = fmaxf(p[10], p[11]);
      float t6 = fmaxf(p[12], p[13]), t7 = fmaxf(p[14], p[15]);
      float u0 = fmaxf(t0, t1), u1 = fmaxf(t2, t3);
      float u2 = fmaxf(t4, t5), u3 = fmaxf(t6, t7);
      pmax = fmaxf(fmaxf(u0, u1), fmaxf(u2, u3));
    }
    pmax = fmaxf(pmax, __shfl_xor(pmax, 32));
    if (!__all(pmax - m_r <= 12.0f)) {
      float mn = fmaxf(m_r, pmax);
      float sf = exp2f(m_r - mn);
      m_r = mn;
      l_r *= sf;
#pragma unroll
      for (int reg = 0; reg < 16; ++reg) {
        float sfr = __shfl(sf, (reg & 3) + 8 * (reg >> 2) + 4 * hi);
#pragma unroll
        for (int nb = 0; nb < 8; ++nb) acc[nb][reg] *= sfr;
      }
    }
#pragma unroll
    for (int i = 0; i < 16; ++i) p[i] = __builtin_amdgcn_exp2f(p[i] - m_r);
    float rs;
    {
      float t0 = p[0] + p[1], t1 = p[2] + p[3];
      float t2 = p[4] + p[5], t3 = p[6] + p[7];
      float t4 = p[8] + p[9], t5 = p[10] + p[11];
      float t6 = p[12] + p[13], t7 = p[14] + p[15];
      float u0 = t0 + t1, u1 = t2 + t3, u2 = t4 + t5, u3 = t6 + t7;
      rs = (u0 + u1) + (u2 + u3);
    }
    rs += __shfl_xor(rs, 32);
    l_r += rs;

    int pk[8];
#pragma unroll
    for (int i = 0; i < 8; ++i) {
      int r;
      asm("v_cvt_pk_bf16_f32 %0, %1, %2"
          : "=v"(r)
          : "v"(p[2 * i]), "v"(p[2 * i + 1]));
      pk[i] = r;
    }
    union PU { int w[4]; bf16x8 v; } pu[2];
#pragma unroll
    for (int kb = 0; kb < 2; ++kb) {
      int base = 4 * kb;
      int pushA = hi ? pk[base + 0] : pk[base + 2];
      int pushB = hi ? pk[base + 1] : pk[base + 3];
      int shA = __shfl_xor(pushA, 32);
      int shB = __shfl_xor(pushB, 32);
      pu[kb].w[0] = hi ? shA : pk[base + 0];
      pu[kb].w[1] = hi ? shB : pk[base + 1];
      pu[kb].w[2] = hi ? pk[base + 2] : shA;
      pu[kb].w[3] = hi ? pk[base + 3] : shB;
    }

    __builtin_amdgcn_s_setprio(1);
#pragma unroll
    for (int nb = 0; nb < 8; ++nb) {
#pragma unroll
      for (int kb = 0; kb < 2; ++kb) {
        bf16x8 vf = *(const bf16x8*)(vB + (kb * 2 + hi) * 4096 +
                                     (nb * 32 + l31) * 16);
        acc[nb] = MFMA32(pu[kb].v, vf, acc[nb], 0, 0, 0);
      }
    }
    __builtin_amdgcn_s_setprio(0);
    __syncthreads();
  }

  float linv = 1.f / l_r;
  unsigned short* Ohp = (half ? Oh1 : Oh0) +
                        ((size_t)b * HW + qt * 128 + wave * 32) * NC;
#pragma unroll
  for (int reg = 0; reg < 16; ++reg) {
    int row = (reg & 3) + 8 * (reg >> 2) + 4 * hi;
    float lr = __shfl(linv, row);
#pragma unroll
    for (int nb = 0; nb < 8; ++nb)
      Ohp[(size_t)row * NC + nb * 32 + l31] = f2bf(acc[nb][reg] * lr);
  }
  if (lane < 32) {
    float* Lp = Lb + (size_t)half * NB * HW;
    Lp[(size_t)b * HW + qt * 128 + wave * 32 + lane] = m_r + log2f(l_r);
  }
}

// ---------------------------------------------------------------- kernel 5
// out = out_w @ merged_att^T + out_b + x. W staged async via global_load_lds
// (issued before the merge-VALU staging so the merge hides load latency).
__global__ __launch_bounds__(256) void outproj_kernel(
    const unsigned short* __restrict__ owb, const float* __restrict__ obias,
    const unsigned short* __restrict__ Oh0, const unsigned short* __restrict__ Oh1,
    const float* __restrict__ Lb, const float* __restrict__ x,
    float* __restrict__ out) {
  int b = blockIdx.y;
  int p0 = blockIdx.x * 64;
  int tid = threadIdx.x;
  int wave = tid >> 6, lane = tid & 63;
  int l15 = lane & 15, q4 = lane >> 4;
  __shared__ unsigned short aw_lds[256 * 64];  // [o][c] swizzled
  __shared__ unsigned short bt_lds[64 * 64];   // [p][c] swizzled
  char* aB = (char*)aw_lds;
  char* bB = (char*)bt_lds;

  unsigned int wsrc[8];
#pragma unroll
  for (int i = 0; i < 8; ++i) {
    int dk = wave * 8192 + i * 1024 + lane * 16;
    int row = dk >> 7;
    wsrc[i] = row * 512 + ((dk & 127) ^ SWZ(row));
  }
  const char* owbb = (const char*)owb;

  f32x4 acc[4][4];
  for (int i = 0; i < 4; ++i)
    for (int j = 0; j < 4; ++j) acc[i][j] = (f32x4){0.f, 0.f, 0.f, 0.f};

  for (int kc0 = 0; kc0 < 256; kc0 += 64) {
    __syncthreads();
    // issue W gloads first (async)
#pragma unroll
    for (int i = 0; i < 8; ++i)
      gload16(owbb + wsrc[i] + kc0 * 2,
              aB + wave * 8192 + i * 1024 + lane * 16);
    // merge-stage att tile (VALU work overlaps the W loads)
    for (int it = 0; it < 2; ++it) {
      int idx = tid + it * 256;
      int p = idx >> 3, c8i = idx & 7;
      int row = p0 + p;
      float L1 = Lb[(size_t)b * HW + row];
      float L2 = Lb[(size_t)(NB + b) * HW + row];
      float w1 = 1.f / (1.f + exp2f(L2 - L1));
      float w2 = 1.f - w1;
      const unsigned short* o1p = Oh0 + ((size_t)b * HW + row) * NC + kc0 + c8i * 8;
      const unsigned short* o2p = Oh1 + ((size_t)b * HW + row) * NC + kc0 + c8i * 8;
      uint4 ra = *(const uint4*)o1p;
      uint4 rb = *(const uint4*)o2p;
      unsigned int aw[4] = {ra.x, ra.y, ra.z, ra.w};
      unsigned int bw[4] = {rb.x, rb.y, rb.z, rb.w};
      unsigned int outw[4];
      for (int i = 0; i < 4; ++i) {
        float lo = w1 * bf2f((unsigned short)(aw[i] & 0xffffu)) +
                   w2 * bf2f((unsigned short)(bw[i] & 0xffffu));
        float hic = w1 * bf2f((unsigned short)(aw[i] >> 16)) +
                    w2 * bf2f((unsigned short)(bw[i] >> 16));
        int r;
        asm("v_cvt_pk_bf16_f32 %0, %1, %2" : "=v"(r) : "v"(lo), "v"(hic));
        outw[i] = (unsigned int)r;
      }
      *(uint4*)(bB + ((p * 128 + c8i * 16) ^ SWZ(p))) =
          make_uint4(outw[0], outw[1], outw[2], outw[3]);
    }
    __syncthreads();
#pragma unroll
    for (int kk = 0; kk < 2; ++kk) {
      bf16x8 af[4], bfv[4];
      for (int obk = 0; obk < 4; ++obk) {
        int row = wave * 64 + obk * 16 + l15;
        af[obk] = *(const bf16x8*)(aB + ((row * 128 + kk * 64 + q4 * 16) ^ SWZ(row)));
      }
      for (int pb = 0; pb < 4; ++pb) {
        int row = pb * 16 + l15;
        bfv[pb] = *(const bf16x8*)(bB + ((row * 128 + kk * 64 + q4 * 16) ^ SWZ(row)));
      }
      for (int obk = 0; obk < 4; ++obk)
        for (int pb = 0; pb < 4; ++pb)
          acc[obk][pb] = MFMA16(af[obk], bfv[pb], acc[obk][pb], 0, 0, 0);
    }
  }
  for (int obk = 0; obk < 4; ++obk)
    for (int pb = 0; pb < 4; ++pb)
      for (int r = 0; r < 4; ++r) {
        int o = wave * 64 + obk * 16 + q4 * 4 + r;
        int p = p0 + pb * 16 + l15;
        size_t gi = ((size_t)b * NC + o) * HW + p;
        out[gi] = acc[obk][pb][r] + obias[o] + x[gi];
      }
}

// ---------------------------------------------------------------- launch
extern "C" void kernel_launch(void* const* d_in, const int* in_sizes, int n_in,
                              void* d_out, int out_size, void* d_ws, size_t ws_size,
                              hipStream_t stream) {
  (void)in_sizes; (void)n_in; (void)out_size; (void)ws_size;
  const float* x = (const float*)d_in[0];
  const float* gnw = (const float*)d_in[1];
  const float* gnb = (const float*)d_in[2];
  const float* qkvw = (const float*)d_in[3];
  const float* qkvb = (const float*)d_in[4];
  const float* ow = (const float*)d_in[5];
  const float* obias = (const float*)d_in[6];
  float* out = (float*)d_out;

  char* ws = (char*)d_ws;
  float* s_arr = (float*)ws;
  float* t_arr = s_arr + NB * NC;
  size_t tsz = (size_t)NB * HW * NC;  // 8M ushort = 16MB
  unsigned short* qb = (unsigned short*)(ws + 16384);
  unsigned short* kc_ = qb + tsz;
  unsigned short* Oh0 = kc_ + tsz;
  unsigned short* vc = Oh0 + tsz;
  unsigned short* Oh1 = vc + tsz;       // xt aliases this region pre-flash
  unsigned short* xt = Oh1;
  float* Lb = (float*)(Oh1 + tsz);      // 2*NB*HW f32 = 256KB
  unsigned short* wb = (unsigned short*)(Lb + 2 * NB * HW);  // 512KB bf16 W
  unsigned short* owb = wb + 196608;

  hipLaunchKernelGGL(gn_stats_kernel, dim3(NB * 32), dim3(256), 0, stream,
                     x, gnw, gnb, s_arr, t_arr);
  hipLaunchKernelGGL(wconv_kernel, dim3(128), dim3(256), 0, stream,
                     qkvw, ow, wb);
  hipLaunchKernelGGL(gn_apply_kernel, dim3(64, 4, NB), dim3(256), 0, stream,
                     x, s_arr, t_arr, xt);
  hipLaunchKernelGGL(qkv_gemm_kernel, dim3(64, 6, NB), dim3(256), 0, stream,
                     xt, wb, qkvb, qb, kc_, vc);
  hipLaunchKernelGGL(flash_attn_kernel, dim3(512), dim3(256), 0, stream,
                     qb, kc_, vc, Oh0, Oh1, Lb);
  hipLaunchKernelGGL(outproj_kernel, dim3(64, NB), dim3(256), 0, stream,
                     owb, obias, Oh0, Oh1, Lb, x, out);
}